// Round 5
// baseline (784.618 us; speedup 1.0000x reference)
//
#include <hip/hip_runtime.h>

#define XD 256
#define NI 128
#define ND 384
#define BATCH 256
#define NFUSED 6   // fused NS iterations (7 squarings total incl. analytic first)
#define NBLK 128
#define NGRP 8
#define GRPSZ 16   // NBLK / NGRP

// ---------------------------------------------------------------------------
// Two-level grid barrier. Monotonic counters in __device__ globals (persist
// across graph replays, never reset). Arrival lines carry ONLY RMWs; spin
// happens on separate per-group flag lines => no reader/RMW line bouncing.
// ---------------------------------------------------------------------------
__device__ unsigned g_grp_arr[NGRP * 32];   // 128B-padded per-group counters
__device__ unsigned g_grp_gen[NGRP * 32];   // 128B-padded per-group release flags
__device__ unsigned g_root = 0;

__device__ __forceinline__ void gridbar(bool wrote)
{
    __syncthreads();
    if (threadIdx.x == 0) {
        const int g = blockIdx.x >> 4;   // group id (16 blocks per group)
        if (wrote)
            __builtin_amdgcn_fence(__ATOMIC_RELEASE, "agent");  // wb L2
        unsigned a = __hip_atomic_fetch_add(&g_grp_arr[g * 32], 1u,
                                            __ATOMIC_ACQ_REL,
                                            __HIP_MEMORY_SCOPE_AGENT);
        unsigned round = a / GRPSZ;
        if ((a % GRPSZ) == GRPSZ - 1u) {          // group leader
            unsigned r = __hip_atomic_fetch_add(&g_root, 1u,
                                                __ATOMIC_ACQ_REL,
                                                __HIP_MEMORY_SCOPE_AGENT);
            if ((r % NGRP) == NGRP - 1u) {        // last group overall
                unsigned gen = r / NGRP + 1u;
#pragma unroll
                for (int i = 0; i < NGRP; ++i)
                    __hip_atomic_store(&g_grp_gen[i * 32], gen,
                                       __ATOMIC_RELEASE,
                                       __HIP_MEMORY_SCOPE_AGENT);
            }
        }
        unsigned target = round + 1u;
        while ((int)(__hip_atomic_load(&g_grp_gen[g * 32], __ATOMIC_ACQUIRE,
                                       __HIP_MEMORY_SCOPE_AGENT) - target) < 0)
            __builtin_amdgcn_s_sleep(2);
        __builtin_amdgcn_fence(__ATOMIC_ACQUIRE, "agent");      // inv L1/L2
    }
    __syncthreads();
}

// ---------------------------------------------------------------------------
// 32x32-tile GEMM accumulate into acc[2][2]. block = 256 threads (tx,ty in 16x16).
// AMODE: 0 = A[m*lda+k]  1 = A[k*lda+m] (transposed)  2 = A[m*lda+k]-A2[m*lda+k]
// BMODE: 0 = B[k*ldb+n]  1 = B[n*ldb+k] (transposed)  2 = 2I - B (plain layout)
// ---------------------------------------------------------------------------
template<int AMODE, int BMODE>
__device__ __forceinline__ void gemm32(
    const float* __restrict__ Ag, const float* __restrict__ A2, int lda,
    const float* __restrict__ Bg, int ldb,
    int m0, int n0, int Kdim,
    float* __restrict__ As, float* __restrict__ Bs,
    int tid, int tx, int ty, float acc[2][2])
{
    for (int k0 = 0; k0 < Kdim; k0 += 32) {
#pragma unroll
        for (int it = 0; it < 4; ++it) {
            int idx = tid + it * 256;
            int mm, kk;
            if (AMODE == 1) { mm = idx & 31; kk = idx >> 5; }
            else           { mm = idx >> 5; kk = idx & 31; }
            float v;
            if (AMODE == 1) v = Ag[(k0 + kk) * lda + (m0 + mm)];
            else            v = Ag[(m0 + mm) * lda + (k0 + kk)];
            if (AMODE == 2) v -= A2[(m0 + mm) * lda + (k0 + kk)];
            As[kk * 34 + mm] = v;
        }
#pragma unroll
        for (int it = 0; it < 4; ++it) {
            int idx = tid + it * 256;
            if (BMODE == 1) {
                int nn = idx >> 5, kk = idx & 31;
                Bs[kk * 34 + nn] = Bg[(n0 + nn) * ldb + (k0 + kk)];
            } else {
                int kk = idx >> 5, nn = idx & 31;
                float v = Bg[(k0 + kk) * ldb + (n0 + nn)];
                if (BMODE == 2) v = ((k0 + kk) == (n0 + nn)) ? 2.0f - v : -v;
                Bs[kk * 34 + nn] = v;
            }
        }
        __syncthreads();
#pragma unroll
        for (int kk = 0; kk < 32; ++kk) {
            float2 a = *(const float2*)(As + kk * 34 + 2 * ty);
            float2 b = *(const float2*)(Bs + kk * 34 + 2 * tx);
            acc[0][0] = fmaf(a.x, b.x, acc[0][0]);
            acc[0][1] = fmaf(a.x, b.y, acc[0][1]);
            acc[1][0] = fmaf(a.y, b.x, acc[1][0]);
            acc[1][1] = fmaf(a.y, b.y, acc[1][1]);
        }
        __syncthreads();
    }
}

// ---------------------------------------------------------------------------
// Entire solve in one cooperative kernel. Grid = 128 blocks x 256 threads.
// ---------------------------------------------------------------------------
__global__ void __launch_bounds__(256)
admm_all(const float* __restrict__ x, const float* __restrict__ parms,
         const float* __restrict__ Q, const float* __restrict__ A,
         float* __restrict__ ws, float* __restrict__ out)
{
    __shared__ float As[32 * 34];
    __shared__ float Bs[32 * 34];
    __shared__ float red[256];
    const int tid = threadIdx.x;
    const int tx = tid & 15, ty = tid >> 4;
    const int bid = blockIdx.x;

    float* Kw   = ws;                       // 256*256
    float* Yb[2] = { ws + 65536, ws + 131072 };
    float* Xb[2] = { ws + 196608, ws + 262144 };
    float* U    = ws + 327680;              // 384*384
    float* Z[2] = { ws + 475136, ws + 573440 };
    float* W    = ws + 671744;

    float* xout  = out;                     // (B, XD)
    float* rgap  = out + BATCH * XD;        // (B, ND)
    float* sgap  = rgap + BATCH * ND;       // (B, ND)
    float* xhist = sgap + BATCH * ND;       // (STEPS+1, B, ND)

    // ---- phase 0: K = A^T A + Q + I  ||  state init ----
    if (bid < 64) {
        int m0 = (bid >> 3) * 32, n0 = (bid & 7) * 32;
        float acc[2][2] = {};
        gemm32<1, 0>(A, nullptr, XD, A, XD, m0, n0, NI, As, Bs, tid, tx, ty, acc);
#pragma unroll
        for (int i = 0; i < 2; ++i)
#pragma unroll
            for (int j = 0; j < 2; ++j) {
                int m = m0 + 2 * ty + i, n = n0 + 2 * tx + j;
                Kw[m * XD + n] = acc[i][j] + Q[m * XD + n] + (m == n ? 1.0f : 0.0f);
            }
    } else {
        int base = (bid - 64) * 256 + tid;
#pragma unroll
        for (int r = 0; r < 6; ++r) {
            int e = base + r * 16384;       // covers BATCH*ND = 98304
            int b = e / ND, i2 = e % ND;
            float v = (i2 < XD) ? x[b * XD + i2] : 0.0f;
            Z[0][e] = v;
            W[e] = 0.0f;
            xhist[e] = v;
        }
    }
    gridbar(true);

    // ---- phase 1: every block redundantly computes c = 2/(2+Gershgorin) ----
    {
        float s = 0.f;
#pragma unroll 8
        for (int j = 0; j < XD; ++j) s += fabsf(Kw[j * XD + tid]);
        red[tid] = s;
        __syncthreads();
        for (int off = 128; off; off >>= 1) {
            if (tid < off) red[tid] = fmaxf(red[tid], red[tid + off]);
            __syncthreads();
        }
    }
    const float c = 2.0f / (2.0f + red[0]);
    __syncthreads();

    // ---- phase 1b: Y1 = 2cK - c^2 K^2  ||  X1 = 2cI - c^2 K ----
    if (bid < 64) {
        int m0 = (bid >> 3) * 32, n0 = (bid & 7) * 32;
        float acc[2][2] = {};
        gemm32<0, 0>(Kw, nullptr, XD, Kw, XD, m0, n0, XD, As, Bs, tid, tx, ty, acc);
#pragma unroll
        for (int i = 0; i < 2; ++i)
#pragma unroll
            for (int j = 0; j < 2; ++j) {
                int m = m0 + 2 * ty + i, n = n0 + 2 * tx + j;
                int g = m * XD + n;
                Yb[0][g] = 2.0f * c * Kw[g] - c * c * acc[i][j];
            }
    } else {
        int base = (bid - 64) * 256 + tid;
#pragma unroll
        for (int r = 0; r < 4; ++r) {
            int e = base + r * 16384;       // covers 65536
            int i2 = e >> 8, j2 = e & 255;
            float v = -c * c * Kw[e];
            if (i2 == j2) v += 2.0f * c;
            Xb[0][e] = v;
        }
    }
    gridbar(true);

    // ---- phases 2..7: fused Newton-Schulz, 2 GEMMs concurrently/phase ----
    int cur = 0;
    for (int it2 = 0; it2 < NFUSED; ++it2) {
        int nxt = cur ^ 1;
        if (bid < 64) {
            int m0 = (bid >> 3) * 32, n0 = (bid & 7) * 32;
            float acc[2][2] = {};
            gemm32<0, 2>(Yb[cur], nullptr, XD, Yb[cur], XD, m0, n0, XD, As, Bs, tid, tx, ty, acc);
#pragma unroll
            for (int i = 0; i < 2; ++i)
#pragma unroll
                for (int j = 0; j < 2; ++j)
                    Yb[nxt][(m0 + 2 * ty + i) * XD + (n0 + 2 * tx + j)] = acc[i][j];
        } else {
            int t = bid - 64;
            int m0 = (t >> 3) * 32, n0 = (t & 7) * 32;
            float acc[2][2] = {};
            gemm32<0, 2>(Xb[cur], nullptr, XD, Yb[cur], XD, m0, n0, XD, As, Bs, tid, tx, ty, acc);
#pragma unroll
            for (int i = 0; i < 2; ++i)
#pragma unroll
                for (int j = 0; j < 2; ++j)
                    Xb[nxt][(m0 + 2 * ty + i) * XD + (n0 + 2 * tx + j)] = acc[i][j];
        }
        cur = nxt;
        gridbar(true);
    }
    const float* Xf = Xb[cur];              // K^{-1}

    // ---- phase 8: U_TR = -X A^T || U_BL = -A X || U_TL = X ----
    if (bid < 32) {
        int m0 = (bid >> 2) * 32, n0 = (bid & 3) * 32;
        float acc[2][2] = {};
        gemm32<0, 1>(Xf, nullptr, XD, A, XD, m0, n0, XD, As, Bs, tid, tx, ty, acc);
#pragma unroll
        for (int i = 0; i < 2; ++i)
#pragma unroll
            for (int j = 0; j < 2; ++j)
                U[(m0 + 2 * ty + i) * ND + XD + (n0 + 2 * tx + j)] = -acc[i][j];
    } else if (bid < 64) {
        int t = bid - 32;
        int m0 = (t >> 3) * 32, n0 = (t & 7) * 32;
        float acc[2][2] = {};
        gemm32<0, 0>(A, nullptr, XD, Xf, XD, m0, n0, XD, As, Bs, tid, tx, ty, acc);
#pragma unroll
        for (int i = 0; i < 2; ++i)
#pragma unroll
            for (int j = 0; j < 2; ++j)
                U[(XD + m0 + 2 * ty + i) * ND + (n0 + 2 * tx + j)] = -acc[i][j];
    } else {
        int base = (bid - 64) * 256 + tid;
#pragma unroll
        for (int r = 0; r < 4; ++r) {
            int e = base + r * 16384;
            int i2 = e >> 8, j2 = e & 255;
            U[i2 * ND + j2] = Xf[e];
        }
    }
    gridbar(true);

    // ---- phase 9: U_BR = -U_BL A^T ----
    if (bid < 16) {
        int m0 = (bid >> 2) * 32, n0 = (bid & 3) * 32;
        float acc[2][2] = {};
        gemm32<0, 1>(U + XD * ND, nullptr, ND, A, XD, m0, n0, XD, As, Bs, tid, tx, ty, acc);
#pragma unroll
        for (int i = 0; i < 2; ++i)
#pragma unroll
            for (int j = 0; j < 2; ++j)
                U[(XD + m0 + 2 * ty + i) * ND + XD + (n0 + 2 * tx + j)] = -acc[i][j];
    }
    gridbar(bid < 16);

    // ---- phases 10..14: 5 ADMM steps ----
    for (int s = 0; s < 5; ++s) {
        const float* zin = Z[s & 1];
        float* zo = Z[(s & 1) ^ 1];
        float* xh = xhist + (size_t)(s + 1) * BATCH * ND;
        if (bid < 96) {
            int m0 = (bid / 12) * 32, n0 = (bid % 12) * 32;
            float acc[2][2] = {};
            gemm32<2, 1>(zin, parms, ND, U, ND, m0, n0, ND, As, Bs, tid, tx, ty, acc);
#pragma unroll
            for (int i = 0; i < 2; ++i)
#pragma unroll
                for (int j = 0; j < 2; ++j) {
                    int m = m0 + 2 * ty + i, n = n0 + 2 * tx + j;
                    int g = m * ND + n;
                    float xk = acc[i][j] + ((n >= XD) ? parms[g] : 0.0f);
                    float zv = zin[g];
                    float wv = W[g];
                    float v = xk + wv;
                    float lo = (n < XD) ? -1000.0f : 0.0f;
                    float ynew = fminf(fmaxf(v, lo), 1000.0f);
                    xh[g] = xk;
                    zo[g] = 2.0f * ynew - v;
                    W[g] = v - ynew;
                    if (s == 4) {
                        rgap[g] = xk - ynew;
                        sgap[g] = ynew - (zv + wv);
                        if (n < XD) xout[m * XD + n] = xk;
                    }
                }
        }
        if (s < 4) gridbar(bid < 96);
    }
}

// ---------------------------------------------------------------------------
extern "C" void kernel_launch(void* const* d_in, const int* in_sizes, int n_in,
                              void* d_out, int out_size, void* d_ws, size_t ws_size,
                              hipStream_t stream)
{
    const float* x     = (const float*)d_in[0];
    const float* parms = (const float*)d_in[1];
    const float* Q     = (const float*)d_in[2];
    const float* A     = (const float*)d_in[3];
    float* ws  = (float*)d_ws;
    float* out = (float*)d_out;

    void* args[] = { (void*)&x, (void*)&parms, (void*)&Q, (void*)&A,
                     (void*)&ws, (void*)&out };
    hipLaunchCooperativeKernel((const void*)admm_all, dim3(NBLK), dim3(256),
                               args, 0, stream);
}

// Round 6
// 448.743 us; speedup vs baseline: 1.7485x; 1.7485x over previous
//
#include <hip/hip_runtime.h>

#define XD 256
#define NI 128
#define ND 384
#define BATCH 256
#define NFUSED 6   // fused NS iterations (7 squarings total incl. analytic first)
#define NBLK 128

// ---------------------------------------------------------------------------
// Coherent (sc1) accessors: bypass the non-coherent per-XCD L2, complete at
// the device coherence point. Used for ALL cross-block rewritten data, so the
// grid barrier needs NO cache-maintenance fences (the ~30us/barrier cost of
// rounds 2/4/5).
// ---------------------------------------------------------------------------
__device__ __forceinline__ float ld_c(const float* p) {
    return __hip_atomic_load(p, __ATOMIC_RELAXED, __HIP_MEMORY_SCOPE_AGENT);
}
__device__ __forceinline__ void st_c(float* p, float v) {
    __hip_atomic_store(p, v, __ATOMIC_RELAXED, __HIP_MEMORY_SCOPE_AGENT);
}

// ---------------------------------------------------------------------------
// Fence-free grid barrier: single monotonic arrival counter (replay-safe,
// never reset). __syncthreads() drains vmcnt(0) => all sc1 stores are at the
// coherence point before thread0 signals arrival. Spin is a relaxed sc1 load
// (NO acquire => no buffer_inv per poll — round 5's mistake).
// ---------------------------------------------------------------------------
__device__ unsigned g_arrive = 0;

__device__ __forceinline__ void gridbar()
{
    __syncthreads();
    if (threadIdx.x == 0) {
        unsigned a = __hip_atomic_fetch_add(&g_arrive, 1u, __ATOMIC_RELAXED,
                                            __HIP_MEMORY_SCOPE_AGENT);
        unsigned target = (a / NBLK + 1u) * NBLK;
        while ((int)(__hip_atomic_load(&g_arrive, __ATOMIC_RELAXED,
                                       __HIP_MEMORY_SCOPE_AGENT) - target) < 0)
            __builtin_amdgcn_s_sleep(1);
    }
    __syncthreads();
}

// ---------------------------------------------------------------------------
// 32x32-tile GEMM accumulate into acc[2][2]. block = 256 threads (tx,ty 16x16).
// AMODE: 0 = A[m*lda+k]  1 = A[k*lda+m] (transposed)  2 = A[m*lda+k]-A2[m*lda+k]
// BMODE: 0 = B[k*ldb+n]  1 = B[n*ldb+k] (transposed)  2 = 2I - B (plain layout)
// ACOH/BCOH: load the A/B operand via coherent (sc1) loads.
// ---------------------------------------------------------------------------
template<int AMODE, int BMODE, bool ACOH, bool BCOH>
__device__ __forceinline__ void gemm32(
    const float* __restrict__ Ag, const float* __restrict__ A2, int lda,
    const float* __restrict__ Bg, int ldb,
    int m0, int n0, int Kdim,
    float* __restrict__ As, float* __restrict__ Bs,
    int tid, int tx, int ty, float acc[2][2])
{
    for (int k0 = 0; k0 < Kdim; k0 += 32) {
#pragma unroll
        for (int it = 0; it < 4; ++it) {
            int idx = tid + it * 256;
            int mm, kk;
            if (AMODE == 1) { mm = idx & 31; kk = idx >> 5; }
            else           { mm = idx >> 5; kk = idx & 31; }
            long off;
            if (AMODE == 1) off = (long)(k0 + kk) * lda + (m0 + mm);
            else            off = (long)(m0 + mm) * lda + (k0 + kk);
            float v = ACOH ? ld_c(Ag + off) : Ag[off];
            if (AMODE == 2) v -= A2[(m0 + mm) * lda + (k0 + kk)];
            As[kk * 34 + mm] = v;
        }
#pragma unroll
        for (int it = 0; it < 4; ++it) {
            int idx = tid + it * 256;
            if (BMODE == 1) {
                int nn = idx >> 5, kk = idx & 31;
                long off = (long)(n0 + nn) * ldb + (k0 + kk);
                Bs[kk * 34 + nn] = BCOH ? ld_c(Bg + off) : Bg[off];
            } else {
                int kk = idx >> 5, nn = idx & 31;
                long off = (long)(k0 + kk) * ldb + (n0 + nn);
                float v = BCOH ? ld_c(Bg + off) : Bg[off];
                if (BMODE == 2) v = ((k0 + kk) == (n0 + nn)) ? 2.0f - v : -v;
                Bs[kk * 34 + nn] = v;
            }
        }
        __syncthreads();
#pragma unroll
        for (int kk = 0; kk < 32; ++kk) {
            float2 a = *(const float2*)(As + kk * 34 + 2 * ty);
            float2 b = *(const float2*)(Bs + kk * 34 + 2 * tx);
            acc[0][0] = fmaf(a.x, b.x, acc[0][0]);
            acc[0][1] = fmaf(a.x, b.y, acc[0][1]);
            acc[1][0] = fmaf(a.y, b.x, acc[1][0]);
            acc[1][1] = fmaf(a.y, b.y, acc[1][1]);
        }
        __syncthreads();
    }
}

// ---------------------------------------------------------------------------
// Entire solve in one cooperative kernel. Grid = 128 blocks x 256 threads.
// ---------------------------------------------------------------------------
__global__ void __launch_bounds__(256)
admm_all(const float* __restrict__ x, const float* __restrict__ parms,
         const float* __restrict__ Q, const float* __restrict__ A,
         float* __restrict__ ws, float* __restrict__ out)
{
    __shared__ float As[32 * 34];
    __shared__ float Bs[32 * 34];
    __shared__ float red[256];
    const int tid = threadIdx.x;
    const int tx = tid & 15, ty = tid >> 4;
    const int bid = blockIdx.x;

    float* Kw   = ws;                       // 256*256 (write-once, sc1-written)
    float* Yb[2] = { ws + 65536, ws + 131072 };
    float* Xb[2] = { ws + 196608, ws + 262144 };
    float* U    = ws + 327680;              // 384*384 (write-once, sc1-written)
    float* Z[2] = { ws + 475136, ws + 573440 };
    float* W    = ws + 671744;

    float* xout  = out;                     // (B, XD)
    float* rgap  = out + BATCH * XD;        // (B, ND)
    float* sgap  = rgap + BATCH * ND;       // (B, ND)
    float* xhist = sgap + BATCH * ND;       // (STEPS+1, B, ND)

    // ---- phase 0: K = A^T A + Q + I  ||  state init ----
    if (bid < 64) {
        int m0 = (bid >> 3) * 32, n0 = (bid & 7) * 32;
        float acc[2][2] = {};
        gemm32<1, 0, false, false>(A, nullptr, XD, A, XD, m0, n0, NI, As, Bs, tid, tx, ty, acc);
#pragma unroll
        for (int i = 0; i < 2; ++i)
#pragma unroll
            for (int j = 0; j < 2; ++j) {
                int m = m0 + 2 * ty + i, n = n0 + 2 * tx + j;
                st_c(&Kw[m * XD + n],
                     acc[i][j] + Q[m * XD + n] + (m == n ? 1.0f : 0.0f));
            }
    } else {
        int base = (bid - 64) * 256 + tid;
#pragma unroll
        for (int r = 0; r < 6; ++r) {
            int e = base + r * 16384;       // covers BATCH*ND = 98304
            int b = e / ND, i2 = e % ND;
            float v = (i2 < XD) ? x[b * XD + i2] : 0.0f;
            st_c(&Z[0][e], v);
            st_c(&W[e], 0.0f);              // cross-block: init here, used by step blocks
            xhist[e] = v;                   // output: host-read only, plain
        }
    }
    gridbar();

    // ---- phase 1: every block redundantly computes c = 2/(2+Gershgorin) ----
    // Kw is write-once => plain cached reads are safe and stay L2-resident.
    {
        float s = 0.f;
#pragma unroll 8
        for (int j = 0; j < XD; ++j) s += fabsf(Kw[j * XD + tid]);
        red[tid] = s;
        __syncthreads();
        for (int off = 128; off; off >>= 1) {
            if (tid < off) red[tid] = fmaxf(red[tid], red[tid + off]);
            __syncthreads();
        }
    }
    const float c = 2.0f / (2.0f + red[0]);
    __syncthreads();

    // ---- phase 1b: Y1 = 2cK - c^2 K^2  ||  X1 = 2cI - c^2 K ----
    if (bid < 64) {
        int m0 = (bid >> 3) * 32, n0 = (bid & 7) * 32;
        float acc[2][2] = {};
        gemm32<0, 0, false, false>(Kw, nullptr, XD, Kw, XD, m0, n0, XD, As, Bs, tid, tx, ty, acc);
#pragma unroll
        for (int i = 0; i < 2; ++i)
#pragma unroll
            for (int j = 0; j < 2; ++j) {
                int m = m0 + 2 * ty + i, n = n0 + 2 * tx + j;
                int g = m * XD + n;
                st_c(&Yb[0][g], 2.0f * c * Kw[g] - c * c * acc[i][j]);
            }
    } else {
        int base = (bid - 64) * 256 + tid;
#pragma unroll
        for (int r = 0; r < 4; ++r) {
            int e = base + r * 16384;       // covers 65536
            int i2 = e >> 8, j2 = e & 255;
            float v = -c * c * Kw[e];
            if (i2 == j2) v += 2.0f * c;
            st_c(&Xb[0][e], v);
        }
    }
    gridbar();

    // ---- phases 2..7: fused Newton-Schulz, 2 GEMMs concurrently/phase ----
    // Yb/Xb are rewritten across barriers => coherent loads AND stores.
    int cur = 0;
    for (int it2 = 0; it2 < NFUSED; ++it2) {
        int nxt = cur ^ 1;
        if (bid < 64) {
            int m0 = (bid >> 3) * 32, n0 = (bid & 7) * 32;
            float acc[2][2] = {};
            gemm32<0, 2, true, true>(Yb[cur], nullptr, XD, Yb[cur], XD, m0, n0, XD, As, Bs, tid, tx, ty, acc);
#pragma unroll
            for (int i = 0; i < 2; ++i)
#pragma unroll
                for (int j = 0; j < 2; ++j)
                    st_c(&Yb[nxt][(m0 + 2 * ty + i) * XD + (n0 + 2 * tx + j)], acc[i][j]);
        } else {
            int t = bid - 64;
            int m0 = (t >> 3) * 32, n0 = (t & 7) * 32;
            float acc[2][2] = {};
            gemm32<0, 2, true, true>(Xb[cur], nullptr, XD, Yb[cur], XD, m0, n0, XD, As, Bs, tid, tx, ty, acc);
#pragma unroll
            for (int i = 0; i < 2; ++i)
#pragma unroll
                for (int j = 0; j < 2; ++j)
                    st_c(&Xb[nxt][(m0 + 2 * ty + i) * XD + (n0 + 2 * tx + j)], acc[i][j]);
        }
        cur = nxt;
        gridbar();
    }
    const float* Xf = Xb[cur];              // K^{-1}

    // ---- phase 8: U_TR = -X A^T || U_BL = -A X || U_TL = X ----
    if (bid < 32) {
        int m0 = (bid >> 2) * 32, n0 = (bid & 3) * 32;
        float acc[2][2] = {};
        gemm32<0, 1, true, false>(Xf, nullptr, XD, A, XD, m0, n0, XD, As, Bs, tid, tx, ty, acc);
#pragma unroll
        for (int i = 0; i < 2; ++i)
#pragma unroll
            for (int j = 0; j < 2; ++j)
                st_c(&U[(m0 + 2 * ty + i) * ND + XD + (n0 + 2 * tx + j)], -acc[i][j]);
    } else if (bid < 64) {
        int t = bid - 32;
        int m0 = (t >> 3) * 32, n0 = (t & 7) * 32;
        float acc[2][2] = {};
        gemm32<0, 0, false, true>(A, nullptr, XD, Xf, XD, m0, n0, XD, As, Bs, tid, tx, ty, acc);
#pragma unroll
        for (int i = 0; i < 2; ++i)
#pragma unroll
            for (int j = 0; j < 2; ++j)
                st_c(&U[(XD + m0 + 2 * ty + i) * ND + (n0 + 2 * tx + j)], -acc[i][j]);
    } else {
        int base = (bid - 64) * 256 + tid;
#pragma unroll
        for (int r = 0; r < 4; ++r) {
            int e = base + r * 16384;
            int i2 = e >> 8, j2 = e & 255;
            st_c(&U[i2 * ND + j2], ld_c(&Xf[e]));
        }
    }
    gridbar();

    // ---- phase 9: U_BR = -U_BL A^T ----
    // U_BL was sc1-written (no stale cached copies) => plain read safe; lines
    // cached here are never rewritten afterwards.
    if (bid < 16) {
        int m0 = (bid >> 2) * 32, n0 = (bid & 3) * 32;
        float acc[2][2] = {};
        gemm32<0, 1, false, false>(U + XD * ND, nullptr, ND, A, XD, m0, n0, XD, As, Bs, tid, tx, ty, acc);
#pragma unroll
        for (int i = 0; i < 2; ++i)
#pragma unroll
            for (int j = 0; j < 2; ++j)
                st_c(&U[(XD + m0 + 2 * ty + i) * ND + XD + (n0 + 2 * tx + j)], -acc[i][j]);
    }
    gridbar();

    // ---- phases 10..14: 5 ADMM steps ----
    // z ping-pongs across barriers => coherent. U is read-only now => plain.
    // W tile is private to this block across all steps => plain.
    for (int s = 0; s < 5; ++s) {
        const float* zin = Z[s & 1];
        float* zo = Z[(s & 1) ^ 1];
        float* xh = xhist + (size_t)(s + 1) * BATCH * ND;
        if (bid < 96) {
            int m0 = (bid / 12) * 32, n0 = (bid % 12) * 32;
            float acc[2][2] = {};
            gemm32<2, 1, true, false>(zin, parms, ND, U, ND, m0, n0, ND, As, Bs, tid, tx, ty, acc);
#pragma unroll
            for (int i = 0; i < 2; ++i)
#pragma unroll
                for (int j = 0; j < 2; ++j) {
                    int m = m0 + 2 * ty + i, n = n0 + 2 * tx + j;
                    int g = m * ND + n;
                    float xk = acc[i][j] + ((n >= XD) ? parms[g] : 0.0f);
                    float zv = ld_c(&zin[g]);
                    float wv = W[g];
                    float v = xk + wv;
                    float lo = (n < XD) ? -1000.0f : 0.0f;
                    float ynew = fminf(fmaxf(v, lo), 1000.0f);
                    xh[g] = xk;
                    st_c(&zo[g], 2.0f * ynew - v);
                    W[g] = v - ynew;
                    if (s == 4) {
                        rgap[g] = xk - ynew;
                        sgap[g] = ynew - (zv + wv);
                        if (n < XD) xout[m * XD + n] = xk;
                    }
                }
        }
        if (s < 4) gridbar();
    }
}

// ---------------------------------------------------------------------------
extern "C" void kernel_launch(void* const* d_in, const int* in_sizes, int n_in,
                              void* d_out, int out_size, void* d_ws, size_t ws_size,
                              hipStream_t stream)
{
    const float* x     = (const float*)d_in[0];
    const float* parms = (const float*)d_in[1];
    const float* Q     = (const float*)d_in[2];
    const float* A     = (const float*)d_in[3];
    float* ws  = (float*)d_ws;
    float* out = (float*)d_out;

    void* args[] = { (void*)&x, (void*)&parms, (void*)&Q, (void*)&A,
                     (void*)&ws, (void*)&out };
    hipLaunchCooperativeKernel((const void*)admm_all, dim3(NBLK), dim3(256),
                               args, 0, stream);
}